// Round 1
// baseline (703.706 us; speedup 1.0000x reference)
//
#include <hip/hip_runtime.h>
#include <math.h>

typedef __bf16 bf16_t;
typedef __bf16 bf16x8_t __attribute__((ext_vector_type(8)));
typedef __bf16 bf16x4_t __attribute__((ext_vector_type(4)));
typedef float f32x4_t __attribute__((ext_vector_type(4)));

#define MFMA(a, b, c) __builtin_amdgcn_mfma_f32_16x16x32_bf16((a), (b), (c), 0, 0, 0)

// ---- workspace layout (bytes) ----
#define WS_WQKV 0u           // 576*192 bf16 = 221184
#define WS_WPROJ 221184u     // 192*192 bf16 = 73728
#define WS_QBIAS 294912u     // 576 f32 = 2304
#define WS_SCALE 297216u     // 6 f32
#define WS_TBL 297472u       // 225*6 f32 = 5400
#define WS_BIAS16 303104u    // 6*64*64 f32 = 98304 -> end 401408

// ============ K1: CPB table: tbl[t][h] = sum_k relu(c@w1^T+b1)[k] * w2[h][k] ============
__global__ __launch_bounds__(64) void cpb_table_kernel(
    const float* __restrict__ w1, const float* __restrict__ b1,
    const float* __restrict__ w2, float* __restrict__ tbl) {
  int t = blockIdx.x;  // 0..224
  int lane = threadIdx.x;
  int dh = t / 15 - 7, dw = t % 15 - 7;
  float th = (float)dh * (8.0f / 7.0f);
  float tw = (float)dw * (8.0f / 7.0f);
  float c0 = copysignf(log2f(fabsf(th) + 1.0f) / 3.0f, th);
  float c1 = copysignf(log2f(fabsf(tw) + 1.0f) / 3.0f, tw);
  float acc[6] = {0.f, 0.f, 0.f, 0.f, 0.f, 0.f};
  for (int k = lane; k < 512; k += 64) {
    float hv = fmaxf(w1[2 * k] * c0 + w1[2 * k + 1] * c1 + b1[k], 0.0f);
#pragma unroll
    for (int hh = 0; hh < 6; ++hh) acc[hh] += hv * w2[hh * 512 + k];
  }
#pragma unroll
  for (int hh = 0; hh < 6; ++hh) {
#pragma unroll
    for (int m = 1; m < 64; m <<= 1) acc[hh] += __shfl_xor(acc[hh], m, 64);
  }
  if (lane == 0) {
#pragma unroll
    for (int hh = 0; hh < 6; ++hh) tbl[t * 6 + hh] = acc[hh];
  }
}

// ============ K2: weight bf16 convert + qkv bias + scales + bias16 gather ============
__global__ __launch_bounds__(256) void prep_kernel(
    const float* __restrict__ qkv_w, const float* __restrict__ proj_w,
    const float* __restrict__ q_bias, const float* __restrict__ v_bias,
    const float* __restrict__ logit_scale, const float* __restrict__ tbl,
    bf16_t* __restrict__ wqkv, bf16_t* __restrict__ wproj,
    float* __restrict__ qbias, float* __restrict__ scalev,
    float* __restrict__ bias16) {
  int id = blockIdx.x * 256 + threadIdx.x;
  if (id < 110592) {
    wqkv[id] = (bf16_t)qkv_w[id];
  } else if (id < 147456) {
    int i = id - 110592;
    wproj[i] = (bf16_t)proj_w[i];
  } else if (id < 148032) {
    int i = id - 147456;
    float bv = (i < 192) ? q_bias[i] : ((i < 384) ? 0.0f : v_bias[i - 384]);
    qbias[i] = bv;
  } else if (id < 148038) {
    int hh = id - 148032;
    scalev[hh] = expf(fminf(logit_scale[hh], logf(100.0f)));
  } else if (id < 172614) {
    int i = id - 148038;  // h*4096 + q*64 + k
    int hh = i >> 12;
    int nm = i & 4095;
    int n = nm >> 6, m = nm & 63;  // n = query token, m = key token
    int i1 = n >> 3, j1 = n & 7, i2 = m >> 3, j2 = m & 7;
    int rpi = (i1 - i2 + 7) * 15 + (j1 - j2 + 7);
    float v = tbl[rpi * 6 + hh];
    bias16[i] = 16.0f / (1.0f + __expf(-v));
  }
}

// ============ main fused kernel: one block = one window, 12 waves = 6 heads x 2 halves ============
// LDS map (bytes):
//  [0,25600)        xs  : x bf16, 64 x stride200       } P aliases [0,55296): 6 x (64 x stride72 bf16)
//  [25600,56320)    qs  : 6 x (64 x stride40 bf16)     }   (valid: xs,q dead after B2)
//  [56320,87040)    ks  : 6 x (64 x stride40 bf16)     } o aliases [56320,81920): 64 x stride200 bf16
//  [87040,114688)   vts : 6 x (32 x stride72 bf16)  [chan][token]
//  [114688,131072)  msk : 64x64 f32
__global__ __launch_bounds__(768) void wattn_kernel(
    const float* __restrict__ x, const float* __restrict__ mask,
    const bf16_t* __restrict__ wqkv, const bf16_t* __restrict__ wproj,
    const float* __restrict__ qbias, const float* __restrict__ scalev,
    const float* __restrict__ bias16, const float* __restrict__ proj_b,
    float* __restrict__ out, int nw) {
  __shared__ __align__(16) char smem[131072];
  bf16_t* xs = (bf16_t*)smem;                  // stride 200
  bf16_t* qs = (bf16_t*)(smem + 25600);        // per head 2560 elems, stride 40
  bf16_t* Ps = (bf16_t*)smem;                  // per head 4608 elems, stride 72
  bf16_t* ksv = (bf16_t*)(smem + 56320);       // per head 2560 elems, stride 40
  bf16_t* os = (bf16_t*)(smem + 56320);        // stride 200
  bf16_t* vts = (bf16_t*)(smem + 87040);       // per head 2304 elems, stride 72
  float* msk = (float*)(smem + 114688);

  const int tid = threadIdx.x;
  const int wave = tid >> 6, lane = tid & 63;
  const int h = wave >> 1, s = wave & 1;
  const int quad = lane >> 4, col = lane & 15;
  const int b = blockIdx.x;

  // ---- phase 0: stage x (fp32->bf16) and mask into LDS ----
  const float4* xg = (const float4*)(x + (size_t)b * 12288);
  for (int i = tid; i < 3072; i += 768) {
    float4 v = xg[i];
    int row = i / 48;
    int c = (i - row * 48) * 4;
    bf16x4_t pk = {(bf16_t)v.x, (bf16_t)v.y, (bf16_t)v.z, (bf16_t)v.w};
    *(bf16x4_t*)(xs + row * 200 + c) = pk;
  }
  const float* mg = mask + (size_t)(b % nw) * 4096;
  for (int i = tid; i < 4096; i += 768) msk[i] = mg[i];
  __syncthreads();  // B1

  const float sc_h = scalev[h];
  const int mrow0 = 32 * s + col;
  const int mrow1 = mrow0 + 16;
  const int koff = quad * 8;
  const f32x4_t zz = {0.f, 0.f, 0.f, 0.f};

  // ---- phase 1: QKV GEMM (this wave: head h cols, token-half s rows) ----
  for (int g = 0; g < 3; ++g) {
    int nbase = g * 192 + h * 32;
    f32x4_t a00 = zz, a01 = zz, a10 = zz, a11 = zz;
#pragma unroll
    for (int kk = 0; kk < 6; ++kk) {
      int k0 = kk * 32 + koff;
      bf16x8_t fa0 = *(const bf16x8_t*)(xs + mrow0 * 200 + k0);
      bf16x8_t fa1 = *(const bf16x8_t*)(xs + mrow1 * 200 + k0);
      bf16x8_t fb0 = *(const bf16x8_t*)(wqkv + (size_t)(nbase + col) * 192 + k0);
      bf16x8_t fb1 = *(const bf16x8_t*)(wqkv + (size_t)(nbase + 16 + col) * 192 + k0);
      a00 = MFMA(fa0, fb0, a00);
      a01 = MFMA(fa0, fb1, a01);
      a10 = MFMA(fa1, fb0, a10);
      a11 = MFMA(fa1, fb1, a11);
    }
    float bn0 = qbias[nbase + col];
    float bn1 = qbias[nbase + 16 + col];
    if (g < 2) {
      // q or k: add bias, L2-normalize rows (head-dim=32 across 16 lanes x 2 tiles), fold scale into q
      float mult = (g == 0) ? sc_h : 1.0f;
      bf16_t* dst = ((g == 0) ? qs : ksv) + h * 2560;
#pragma unroll
      for (int mi2 = 0; mi2 < 2; ++mi2) {
        f32x4_t va = mi2 ? a10 : a00;
        f32x4_t vb = mi2 ? a11 : a01;
#pragma unroll
        for (int r = 0; r < 4; ++r) {
          float v0 = va[r] + bn0, v1 = vb[r] + bn1;
          float ss = v0 * v0 + v1 * v1;
          ss += __shfl_xor(ss, 1, 64);
          ss += __shfl_xor(ss, 2, 64);
          ss += __shfl_xor(ss, 4, 64);
          ss += __shfl_xor(ss, 8, 64);
          float inv = mult / fmaxf(sqrtf(ss), 1e-12f);
          int token = (2 * s + mi2) * 16 + quad * 4 + r;
          dst[token * 40 + col] = (bf16_t)(v0 * inv);
          dst[token * 40 + 16 + col] = (bf16_t)(v1 * inv);
        }
      }
    } else {
      // v: add bias, store transposed [chan][token] for PV B-operand
      bf16_t* dst = vts + h * 2304;
#pragma unroll
      for (int mi2 = 0; mi2 < 2; ++mi2) {
        f32x4_t va = mi2 ? a10 : a00;
        f32x4_t vb = mi2 ? a11 : a01;
#pragma unroll
        for (int r = 0; r < 4; ++r) {
          int token = (2 * s + mi2) * 16 + quad * 4 + r;
          dst[col * 72 + token] = (bf16_t)(va[r] + bn0);
          dst[(16 + col) * 72 + token] = (bf16_t)(vb[r] + bn1);
        }
      }
    }
  }
  __syncthreads();  // B1.5: k/v of both halves visible

  // ---- phase 2: attn = (scaled qn) @ kn^T, K=32 single MFMA step ----
  f32x4_t at[2][4];
  {
    const bf16_t* qh = qs + h * 2560;
    const bf16_t* kh = ksv + h * 2560;
    bf16x8_t aq0 = *(const bf16x8_t*)(qh + mrow0 * 40 + koff);
    bf16x8_t aq1 = *(const bf16x8_t*)(qh + mrow1 * 40 + koff);
#pragma unroll
    for (int ni = 0; ni < 4; ++ni) {
      bf16x8_t bk = *(const bf16x8_t*)(kh + (ni * 16 + col) * 40 + koff);
      at[0][ni] = MFMA(aq0, bk, zz);
      at[1][ni] = MFMA(aq1, bk, zz);
    }
  }

  // ---- softmax rows (in-register; + cpb bias from L2, + mask from LDS) ----
  float p[2][4][4];
  const float* bg = bias16 + h * 4096;
#pragma unroll
  for (int mi2 = 0; mi2 < 2; ++mi2) {
#pragma unroll
    for (int r = 0; r < 4; ++r) {
      int m = (2 * s + mi2) * 16 + quad * 4 + r;
      float vals[4];
#pragma unroll
      for (int ni = 0; ni < 4; ++ni) {
        int n = ni * 16 + col;
        vals[ni] = at[mi2][ni][r] + bg[m * 64 + n] + msk[m * 64 + n];
      }
      float mx = fmaxf(fmaxf(vals[0], vals[1]), fmaxf(vals[2], vals[3]));
      mx = fmaxf(mx, __shfl_xor(mx, 1, 64));
      mx = fmaxf(mx, __shfl_xor(mx, 2, 64));
      mx = fmaxf(mx, __shfl_xor(mx, 4, 64));
      mx = fmaxf(mx, __shfl_xor(mx, 8, 64));
      float sm = 0.f;
#pragma unroll
      for (int ni = 0; ni < 4; ++ni) {
        vals[ni] = __expf(vals[ni] - mx);
        sm += vals[ni];
      }
      sm += __shfl_xor(sm, 1, 64);
      sm += __shfl_xor(sm, 2, 64);
      sm += __shfl_xor(sm, 4, 64);
      sm += __shfl_xor(sm, 8, 64);
      float inv = 1.0f / sm;
#pragma unroll
      for (int ni = 0; ni < 4; ++ni) p[mi2][ni][r] = vals[ni] * inv;
    }
  }
  __syncthreads();  // B2: xs/q/k/mask reads all done -> safe to alias with P and o

  // ---- write P (bf16, A-operand layout source) ----
  bf16_t* Ph = Ps + h * 4608;
#pragma unroll
  for (int mi2 = 0; mi2 < 2; ++mi2) {
#pragma unroll
    for (int ni = 0; ni < 4; ++ni) {
#pragma unroll
      for (int r = 0; r < 4; ++r) {
        int m = (2 * s + mi2) * 16 + quad * 4 + r;
        Ph[m * 72 + ni * 16 + col] = (bf16_t)p[mi2][ni][r];
      }
    }
  }

  // ---- phase 3: O_h = P @ V (K=64 -> 2 steps) ----
  f32x4_t oac[2][2] = {{zz, zz}, {zz, zz}};
  {
    const bf16_t* vh = vts + h * 2304;
#pragma unroll
    for (int kk = 0; kk < 2; ++kk) {
      int k0 = kk * 32 + koff;
      bf16x8_t pa0 = *(const bf16x8_t*)(Ph + mrow0 * 72 + k0);
      bf16x8_t pa1 = *(const bf16x8_t*)(Ph + mrow1 * 72 + k0);
      bf16x8_t vb0 = *(const bf16x8_t*)(vh + col * 72 + k0);
      bf16x8_t vb1 = *(const bf16x8_t*)(vh + (16 + col) * 72 + k0);
      oac[0][0] = MFMA(pa0, vb0, oac[0][0]);
      oac[0][1] = MFMA(pa0, vb1, oac[0][1]);
      oac[1][0] = MFMA(pa1, vb0, oac[1][0]);
      oac[1][1] = MFMA(pa1, vb1, oac[1][1]);
    }
  }
  // stage o (all heads' 32-ch slices -> 64x192, stride 200)
#pragma unroll
  for (int mi2 = 0; mi2 < 2; ++mi2) {
#pragma unroll
    for (int ni = 0; ni < 2; ++ni) {
#pragma unroll
      for (int r = 0; r < 4; ++r) {
        int token = (2 * s + mi2) * 16 + quad * 4 + r;
        os[token * 200 + h * 32 + ni * 16 + col] = (bf16_t)oac[mi2][ni][r];
      }
    }
  }
  __syncthreads();  // B3: full o visible

  // ---- phase 4: out = o @ proj_w^T + proj_b (this wave: cols 32h..32h+31, rows half s) ----
  f32x4_t pr[2][2] = {{zz, zz}, {zz, zz}};
#pragma unroll
  for (int kk = 0; kk < 6; ++kk) {
    int k0 = kk * 32 + koff;
    bf16x8_t fa0 = *(const bf16x8_t*)(os + mrow0 * 200 + k0);
    bf16x8_t fa1 = *(const bf16x8_t*)(os + mrow1 * 200 + k0);
    bf16x8_t fb0 = *(const bf16x8_t*)(wproj + (size_t)(h * 32 + col) * 192 + k0);
    bf16x8_t fb1 = *(const bf16x8_t*)(wproj + (size_t)(h * 32 + 16 + col) * 192 + k0);
    pr[0][0] = MFMA(fa0, fb0, pr[0][0]);
    pr[0][1] = MFMA(fa0, fb1, pr[0][1]);
    pr[1][0] = MFMA(fa1, fb0, pr[1][0]);
    pr[1][1] = MFMA(fa1, fb1, pr[1][1]);
  }
  float pb0 = proj_b[h * 32 + col];
  float pb1 = proj_b[h * 32 + 16 + col];
  float* og = out + (size_t)b * 12288;
#pragma unroll
  for (int mi2 = 0; mi2 < 2; ++mi2) {
#pragma unroll
    for (int r = 0; r < 4; ++r) {
      int token = (2 * s + mi2) * 16 + quad * 4 + r;
      og[token * 192 + h * 32 + col] = pr[mi2][0][r] + pb0;
      og[token * 192 + h * 32 + 16 + col] = pr[mi2][1][r] + pb1;
    }
  }
}

extern "C" void kernel_launch(void* const* d_in, const int* in_sizes, int n_in,
                              void* d_out, int out_size, void* d_ws, size_t ws_size,
                              hipStream_t stream) {
  const float* x = (const float*)d_in[0];
  const float* mask = (const float*)d_in[1];
  const float* qkv_w = (const float*)d_in[2];
  const float* q_bias = (const float*)d_in[3];
  const float* v_bias = (const float*)d_in[4];
  const float* logit_scale = (const float*)d_in[5];
  const float* cpb_w1 = (const float*)d_in[6];
  const float* cpb_b1 = (const float*)d_in[7];
  const float* cpb_w2 = (const float*)d_in[8];
  const float* proj_w = (const float*)d_in[9];
  const float* proj_b = (const float*)d_in[10];
  float* out = (float*)d_out;

  char* ws = (char*)d_ws;
  bf16_t* wqkv = (bf16_t*)(ws + WS_WQKV);
  bf16_t* wproj = (bf16_t*)(ws + WS_WPROJ);
  float* qbias = (float*)(ws + WS_QBIAS);
  float* scalev = (float*)(ws + WS_SCALE);
  float* tbl = (float*)(ws + WS_TBL);
  float* bias16 = (float*)(ws + WS_BIAS16);

  const int nwin = in_sizes[0] / 12288;   // 4096
  const int nw = in_sizes[1] / 4096;      // 64 mask windows

  cpb_table_kernel<<<dim3(225), dim3(64), 0, stream>>>(cpb_w1, cpb_b1, cpb_w2, tbl);
  prep_kernel<<<dim3(675), dim3(256), 0, stream>>>(qkv_w, proj_w, q_bias, v_bias,
                                                   logit_scale, tbl, wqkv, wproj,
                                                   qbias, scalev, bias16);
  wattn_kernel<<<dim3(nwin), dim3(768), 0, stream>>>(x, mask, wqkv, wproj, qbias,
                                                     scalev, bias16, proj_b, out, nw);
}